// Round 4
// baseline (20486.998 us; speedup 1.0000x reference)
//
#include <hip/hip_runtime.h>
#include <hip/hip_fp16.h>
#include <stdint.h>

// LSTM-like scan, T=4096, E=1024, H=1024.
// Phase 1: xpre4[t][row][g] = (x @ U_g^T + B_g)  fp16, row-major interleaved gates
// Phase 2: persistent 256-WG x 256-thread kernel. One WAVE per h-row:
//   lane k owns all 4 gates of its row over h-chunk [16k,16k+16):
//   32 weight dwords/lane (loop-invariant -> register-resident via LICM),
//   32 v_dot2 per step, 6-level shfl_xor reduce, lane-0 epilogue.
//   Wave 0 polls the tagged h buffer (8 x u64 agent loads/lane), packs to LDS,
//   ONE barrier/step. h broadcast: ((epoch)<<16)|fp16 tagged dwords,
//   double-buffered by epoch parity, agent-scope relaxed atomics.

#define T_STEPS 4096
#define HDIM 1024
#define NWG 256

typedef _Float16 half2v __attribute__((ext_vector_type(2)));
typedef uint32_t u32x4 __attribute__((ext_vector_type(4)));

__device__ __forceinline__ float dot2(uint32_t a, uint32_t b, float c) {
#if __has_builtin(__builtin_amdgcn_fdot2)
  return __builtin_amdgcn_fdot2(__builtin_bit_cast(half2v, a),
                                __builtin_bit_cast(half2v, b), c, false);
#else
  half2v av = __builtin_bit_cast(half2v, a);
  half2v bv = __builtin_bit_cast(half2v, b);
  return c + (float)av.x * (float)bv.x + (float)av.y * (float)bv.y;
#endif
}

__device__ __forceinline__ float sigf(float z) { return 1.f / (1.f + __expf(-z)); }

// ---- weight repack: gate f32 [1024][1024] x4 -> per-lane-packed fp16 dwords ----
// Global lane L = wg*256 + tid; wave = tid>>6, lane = tid&63.
// row = wg*4 + wave. Lane block = 32 dwords, i = g*8 + ic -> cols 16*lane + 2*ic.
__global__ __launch_bounds__(256) void convw(const float* __restrict__ w0,
                                             const float* __restrict__ w1,
                                             const float* __restrict__ w2,
                                             const float* __restrict__ w3,
                                             uint32_t* __restrict__ dst) {
  int o = blockIdx.x * 256 + threadIdx.x;  // 0 .. 2M-1 output dwords
  int i = o & 31;
  int L = o >> 5;
  int tidl = L & 255;
  int wg = L >> 8;
  int wave = tidl >> 6, lane = tidl & 63;
  int row = (wg << 2) + wave;
  int g = i >> 3, ic = i & 7;
  int col = (lane << 4) + (ic << 1);
  const float* src = g == 0 ? w0 : g == 1 ? w1 : g == 2 ? w2 : w3;
  float2 v = *(const float2*)(src + (size_t)row * 1024 + col);
  uint32_t dw = (uint32_t)__half_as_ushort(__float2half(v.x)) |
                ((uint32_t)__half_as_ushort(__float2half(v.y)) << 16);
  dst[o] = dw;
}

// ---------------- zero the tagged h broadcast buffers (2 x 1024 dwords) --------
__global__ void zerok(uint32_t* __restrict__ p) {
  int i = blockIdx.x * 256 + threadIdx.x;
  if (i < 2048) p[i] = 0;
}

// ---------------- fp32 GEMM: xpre4[t][j][g] = x[t][:] . U_g[j][:] + B_g[j] -----
__global__ __launch_bounds__(256) void gemmk(
    const float* __restrict__ x,
    const float* __restrict__ u0, const float* __restrict__ u1,
    const float* __restrict__ u2, const float* __restrict__ u3,
    const float* __restrict__ b0, const float* __restrict__ b1,
    const float* __restrict__ b2, const float* __restrict__ b3,
    __half* __restrict__ xpre4) {
  __shared__ float As[64][33];
  __shared__ float Bs[64][33];
  const int tid = threadIdx.x;
  const int m0 = blockIdx.y * 64;
  const int n0 = blockIdx.x * 64;
  const int g = n0 >> 10;
  const float* Up = g == 0 ? u0 : g == 1 ? u1 : g == 2 ? u2 : u3;
  const float* Bp = g == 0 ? b0 : g == 1 ? b1 : g == 2 ? b2 : b3;
  const int j0 = n0 & 1023;
  const int tx = tid & 15, ty = tid >> 4;
  const int lr = tid >> 3, lc = (tid & 7) << 2;
  float acc[4][4] = {};
  for (int k0 = 0; k0 < 1024; k0 += 32) {
    float4 a0 = *(const float4*)&x[(size_t)(m0 + lr) * 1024 + k0 + lc];
    float4 a1 = *(const float4*)&x[(size_t)(m0 + lr + 32) * 1024 + k0 + lc];
    float4 c0 = *(const float4*)&Up[(size_t)(j0 + lr) * 1024 + k0 + lc];
    float4 c1 = *(const float4*)&Up[(size_t)(j0 + lr + 32) * 1024 + k0 + lc];
    __syncthreads();
    As[lr][lc + 0] = a0.x; As[lr][lc + 1] = a0.y; As[lr][lc + 2] = a0.z; As[lr][lc + 3] = a0.w;
    As[lr + 32][lc + 0] = a1.x; As[lr + 32][lc + 1] = a1.y; As[lr + 32][lc + 2] = a1.z; As[lr + 32][lc + 3] = a1.w;
    Bs[lr][lc + 0] = c0.x; Bs[lr][lc + 1] = c0.y; Bs[lr][lc + 2] = c0.z; Bs[lr][lc + 3] = c0.w;
    Bs[lr + 32][lc + 0] = c1.x; Bs[lr + 32][lc + 1] = c1.y; Bs[lr + 32][lc + 2] = c1.z; Bs[lr + 32][lc + 3] = c1.w;
    __syncthreads();
#pragma unroll
    for (int k = 0; k < 32; ++k) {
      float a0v = As[ty * 4 + 0][k], a1v = As[ty * 4 + 1][k];
      float a2v = As[ty * 4 + 2][k], a3v = As[ty * 4 + 3][k];
      float b0v = Bs[tx * 4 + 0][k], b1v = Bs[tx * 4 + 1][k];
      float b2v = Bs[tx * 4 + 2][k], b3v = Bs[tx * 4 + 3][k];
      acc[0][0] += a0v * b0v; acc[0][1] += a0v * b1v; acc[0][2] += a0v * b2v; acc[0][3] += a0v * b3v;
      acc[1][0] += a1v * b0v; acc[1][1] += a1v * b1v; acc[1][2] += a1v * b2v; acc[1][3] += a1v * b3v;
      acc[2][0] += a2v * b0v; acc[2][1] += a2v * b1v; acc[2][2] += a2v * b2v; acc[2][3] += a2v * b3v;
      acc[3][0] += a3v * b0v; acc[3][1] += a3v * b1v; acc[3][2] += a3v * b2v; acc[3][3] += a3v * b3v;
    }
  }
  // scatter epilogue: xpre4[(t*1024 + j)*4 + g]
#pragma unroll
  for (int i = 0; i < 4; ++i) {
    size_t rowi = (size_t)(m0 + ty * 4 + i);
#pragma unroll
    for (int j = 0; j < 4; ++j) {
      int jj = j0 + tx * 4 + j;
      float v = acc[i][j] + Bp[jj];
      xpre4[(rowi * 1024 + jj) * 4 + g] = __float2half(v);
    }
  }
}

// ---------------- persistent recurrence kernel --------------------------------
__global__ __launch_bounds__(256, 1) void rnnk(
    const uint32_t* __restrict__ wpack,  // [256][256][32] dwords, per-lane packed
    const __half* __restrict__ xpre4,    // [4096][1024][4] fp16
    uint32_t* tagged,                    // [2][1024] tagged h dwords
    float* __restrict__ out) {           // [4096][1024] f32
  __shared__ uint32_t hl[2][512];        // packed h pairs, double-buffered
  const int wg = blockIdx.x;
  const int tid = threadIdx.x;
  const int wave = tid >> 6, lane = tid & 63;
  const int row = (wg << 2) + wave;      // one wave per h-row
  const bool w0 = (wave == 0);
  const bool leader = (lane == 0);

  // ---- 32 weight dwords (4 gates x 16 fp16 over cols [16*lane,16*lane+16)) ----
  // Loop-invariant; low total pressure (~80 VGPR) => compiler keeps them resident.
  u32x4 W[8];
  {
    const u32x4* wp =
        reinterpret_cast<const u32x4*>(wpack) + (((size_t)wg << 8) + tid) * 8;
#pragma unroll
    for (int i = 0; i < 8; ++i) W[i] = wp[i];
  }

  float s = 0.f;  // cell state (leader lanes only)

  for (int t = 0; t < T_STEPS; ++t) {
    const int buf = t & 1;

    // leader prefetch: all 4 gate pre-activations in ONE 8B load
    float xf = 0.f, xc = 0.f, xg = 0.f, xq = 0.f;
    if (leader) {
      uint2 xv = *reinterpret_cast<const uint2*>(
          reinterpret_cast<const uint32_t*>(xpre4) + ((((size_t)t << 10) + row) << 1));
      __half2 lo = __builtin_bit_cast(__half2, xv.x);
      __half2 hi = __builtin_bit_cast(__half2, xv.y);
      xf = __half2float(lo.x); xc = __half2float(lo.y);
      xg = __half2float(hi.x); xq = __half2float(hi.y);
    }

    // --- wave 0: poll h_{t-1} (16 tagged dwords/lane), pack into LDS ---
    if (w0) {
      const unsigned long long* pp =
          reinterpret_cast<const unsigned long long*>(tagged + (buf << 10)) +
          (lane << 3);
      const uint32_t tg = (uint32_t)t;
      unsigned long long v[8];
      bool ok;
      do {
#pragma unroll
        for (int j = 0; j < 8; ++j)
          v[j] = __hip_atomic_load(pp + j, __ATOMIC_RELAXED, __HIP_MEMORY_SCOPE_AGENT);
        ok = true;
#pragma unroll
        for (int j = 0; j < 8; ++j)
          ok = ok && (((uint32_t)(v[j] >> 16) & 0xffffu) == tg) &&
               ((uint32_t)(v[j] >> 48) == tg);
      } while (!ok);
      uint32_t pk[8];
#pragma unroll
      for (int j = 0; j < 8; ++j)
        pk[j] = (uint32_t)(v[j] & 0xffffu) | (((uint32_t)(v[j] >> 32) & 0xffffu) << 16);
      u32x4 wA, wB;
      wA.x = pk[0]; wA.y = pk[1]; wA.z = pk[2]; wA.w = pk[3];
      wB.x = pk[4]; wB.y = pk[5]; wB.z = pk[6]; wB.w = pk[7];
      uint32_t* dst = &hl[buf][lane << 3];
      *reinterpret_cast<u32x4*>(dst) = wA;
      *reinterpret_cast<u32x4*>(dst + 4) = wB;
    }
    __syncthreads();  // hl[buf] ready — the only barrier per step

    // --- own chunk: 8 packed dwords = h[16*lane .. 16*lane+16) ---
    u32x4 h0 = *reinterpret_cast<const u32x4*>(&hl[buf][lane << 3]);
    u32x4 h1 = *reinterpret_cast<const u32x4*>(&hl[buf][(lane << 3) + 4]);

    // --- 4 gates x 32 MACs ---
    float a0 = 0.f, a1 = 0.f, a2 = 0.f, a3 = 0.f;
    a0 = dot2(W[0].x, h0.x, a0); a0 = dot2(W[0].y, h0.y, a0);
    a0 = dot2(W[0].z, h0.z, a0); a0 = dot2(W[0].w, h0.w, a0);
    a0 = dot2(W[1].x, h1.x, a0); a0 = dot2(W[1].y, h1.y, a0);
    a0 = dot2(W[1].z, h1.z, a0); a0 = dot2(W[1].w, h1.w, a0);
    a1 = dot2(W[2].x, h0.x, a1); a1 = dot2(W[2].y, h0.y, a1);
    a1 = dot2(W[2].z, h0.z, a1); a1 = dot2(W[2].w, h0.w, a1);
    a1 = dot2(W[3].x, h1.x, a1); a1 = dot2(W[3].y, h1.y, a1);
    a1 = dot2(W[3].z, h1.z, a1); a1 = dot2(W[3].w, h1.w, a1);
    a2 = dot2(W[4].x, h0.x, a2); a2 = dot2(W[4].y, h0.y, a2);
    a2 = dot2(W[4].z, h0.z, a2); a2 = dot2(W[4].w, h0.w, a2);
    a2 = dot2(W[5].x, h1.x, a2); a2 = dot2(W[5].y, h1.y, a2);
    a2 = dot2(W[5].z, h1.z, a2); a2 = dot2(W[5].w, h1.w, a2);
    a3 = dot2(W[6].x, h0.x, a3); a3 = dot2(W[6].y, h0.y, a3);
    a3 = dot2(W[6].z, h0.z, a3); a3 = dot2(W[6].w, h0.w, a3);
    a3 = dot2(W[7].x, h1.x, a3); a3 = dot2(W[7].y, h1.y, a3);
    a3 = dot2(W[7].z, h1.z, a3); a3 = dot2(W[7].w, h1.w, a3);

    // --- in-wave reduce across 64 chunk-lanes ---
#pragma unroll
    for (int mk = 1; mk <= 32; mk <<= 1) {
      a0 += __shfl_xor(a0, mk);
      a1 += __shfl_xor(a1, mk);
      a2 += __shfl_xor(a2, mk);
      a3 += __shfl_xor(a3, mk);
    }

    // --- leader epilogue: gates, s-update, h, publish ---
    if (leader) {
      float f = sigf(a0 + xf);
      float cc = sigf(a1 + xc);
      float gg = sigf(a2 + xg);
      float q = sigf(a3 + xq);
      s = f * s + gg * cc;
      float e2 = __expf(2.f * s);  // s >= 0 always; inf -> th = 1
      float th = 1.f - 2.f / (e2 + 1.f);
      float h = th * q;
      out[(size_t)t * HDIM + row] = h;
      uint32_t dw = ((uint32_t)(t + 1) << 16) |
                    (uint32_t)__half_as_ushort(__float2half(h));
      __hip_atomic_store(&tagged[(((t + 1) & 1) << 10) + row], dw,
                         __ATOMIC_RELAXED, __HIP_MEMORY_SCOPE_AGENT);
    }
    // no trailing barrier: hl[buf^1] is written next, and wave0's poll for t+1
    // succeeds only after every row published t+1, i.e. after every wave here
    // finished reading hl[buf].
  }
}

extern "C" void kernel_launch(void* const* d_in, const int* in_sizes, int n_in,
                              void* d_out, int out_size, void* d_ws, size_t ws_size,
                              hipStream_t stream) {
  const float* x  = (const float*)d_in[0];
  const float* Uf = (const float*)d_in[1];
  const float* Wf = (const float*)d_in[2];
  const float* Bf = (const float*)d_in[3];
  const float* Ug = (const float*)d_in[4];
  const float* Wg = (const float*)d_in[5];
  const float* Bg = (const float*)d_in[6];
  const float* Uq = (const float*)d_in[7];
  const float* Wq = (const float*)d_in[8];
  const float* Bq = (const float*)d_in[9];
  const float* U  = (const float*)d_in[10];
  const float* W  = (const float*)d_in[11];
  const float* B  = (const float*)d_in[12];
  float* out = (float*)d_out;

  // ws layout: [0,32MB) xpre4 fp16 [4096][1024][4]; [32MB,40MB) wpack 2M dwords;
  // [40MB,+8KB) tagged h dwords [2][1024].
  char* ws = (char*)d_ws;
  __half* xpre4 = (__half*)ws;
  uint32_t* wpack = (uint32_t*)(ws + (size_t)32 * 1024 * 1024);
  uint32_t* tagged = (uint32_t*)(ws + (size_t)40 * 1024 * 1024);

  // gate order everywhere: 0=f(Uf,Wf,Bf) 1=c(U,W,B) 2=g(Ug,Wg,Bg) 3=q(Uq,Wq,Bq)
  convw<<<8192, 256, 0, stream>>>(Wf, W, Wg, Wq, wpack);
  zerok<<<8, 256, 0, stream>>>(tagged);
  gemmk<<<dim3(64, 64), 256, 0, stream>>>(x, Uf, U, Ug, Uq, Bf, B, Bg, Bq, xpre4);
  rnnk<<<NWG, 256, 0, stream>>>(wpack, xpre4, tagged, out);
}

// Round 5
// 10043.195 us; speedup vs baseline: 2.0399x; 2.0399x over previous
//
#include <hip/hip_runtime.h>
#include <hip/hip_fp16.h>
#include <stdint.h>

// LSTM-like scan, T=4096, E=1024, H=1024.
// Phase 1: xpre4[t][row][g] = (x @ U_g^T + B_g)  fp16, gate-interleaved
// Phase 2: persistent 64-WG x 512-thread kernel, 16 rows/WG.
//   Weights live in LDS (128 KB/WG, bank-swizzled). Each iteration the 16
//   weight quads are ds_read into registers BEFORE the poll/barrier (barrier
//   pins them; LDS service overlaps the poll wait; LDS values are not
//   rematerializable so the allocator must keep them resident).
//   h broadcast: ((epoch)<<16)|fp16 tagged dwords, double-buffered by parity;
//   wave 0 polls with global_load_dwordx4 sc0 sc1 (device-coherent 16B reads),
//   packs pairs into LDS; ONE barrier/step; in-half shfl reduce; lane-0 of
//   each row half does the epilogue and publishes via agent-scope store.

#define T_STEPS 4096
#define HDIM 1024
#define NWG 64

typedef _Float16 half2v __attribute__((ext_vector_type(2)));
typedef uint32_t u32x4 __attribute__((ext_vector_type(4)));

__device__ __forceinline__ float dot2(uint32_t a, uint32_t b, float c) {
#if __has_builtin(__builtin_amdgcn_fdot2)
  return __builtin_amdgcn_fdot2(__builtin_bit_cast(half2v, a),
                                __builtin_bit_cast(half2v, b), c, false);
#else
  half2v av = __builtin_bit_cast(half2v, a);
  half2v bv = __builtin_bit_cast(half2v, b);
  return c + (float)av.x * (float)bv.x + (float)av.y * (float)bv.y;
#endif
}

__device__ __forceinline__ float sigf(float z) { return 1.f / (1.f + __expf(-z)); }

// ---- weight repack: gate f32 [1024][1024] x4 -> per-lane-packed fp16 dwords ----
// Lane lg = wg*512+tid: row = (wg<<4)+(tid>>5), k = tid&31.
// Lane block = 64 dwords: i = g*16 + ic, covering cols 32k+2*ic, +1.
__global__ __launch_bounds__(256) void convw(const float* __restrict__ w0,
                                             const float* __restrict__ w1,
                                             const float* __restrict__ w2,
                                             const float* __restrict__ w3,
                                             uint32_t* __restrict__ dst) {
  int o = blockIdx.x * 256 + threadIdx.x;  // 0 .. 2M-1 output dwords
  int i = o & 63;
  int lg = o >> 6;
  int wg = lg >> 9, tidl = lg & 511;
  int k = tidl & 31, rloc = tidl >> 5;
  int row = (wg << 4) + rloc;
  int g = i >> 4, ic = i & 15;
  int col = (k << 5) + (ic << 1);
  const float* src = g == 0 ? w0 : g == 1 ? w1 : g == 2 ? w2 : w3;
  float2 v = *(const float2*)(src + (size_t)row * 1024 + col);
  uint32_t dw = (uint32_t)__half_as_ushort(__float2half(v.x)) |
                ((uint32_t)__half_as_ushort(__float2half(v.y)) << 16);
  dst[o] = dw;
}

// ---------------- zero the tagged h broadcast buffers (2 x 1024 dwords) --------
__global__ void zerok(uint32_t* __restrict__ p) {
  int i = blockIdx.x * 256 + threadIdx.x;
  if (i < 2048) p[i] = 0;
}

// ---------------- fp32 GEMM: xpre4[t][j][g] = x[t][:] . U_g[j][:] + B_g[j] -----
__global__ __launch_bounds__(256) void gemmk(
    const float* __restrict__ x,
    const float* __restrict__ u0, const float* __restrict__ u1,
    const float* __restrict__ u2, const float* __restrict__ u3,
    const float* __restrict__ b0, const float* __restrict__ b1,
    const float* __restrict__ b2, const float* __restrict__ b3,
    __half* __restrict__ xpre4) {
  __shared__ float As[64][33];
  __shared__ float Bs[64][33];
  const int tid = threadIdx.x;
  const int m0 = blockIdx.y * 64;
  const int n0 = blockIdx.x * 64;
  const int g = n0 >> 10;
  const float* Up = g == 0 ? u0 : g == 1 ? u1 : g == 2 ? u2 : u3;
  const float* Bp = g == 0 ? b0 : g == 1 ? b1 : g == 2 ? b2 : b3;
  const int j0 = n0 & 1023;
  const int tx = tid & 15, ty = tid >> 4;
  const int lr = tid >> 3, lc = (tid & 7) << 2;
  float acc[4][4] = {};
  for (int k0 = 0; k0 < 1024; k0 += 32) {
    float4 a0 = *(const float4*)&x[(size_t)(m0 + lr) * 1024 + k0 + lc];
    float4 a1 = *(const float4*)&x[(size_t)(m0 + lr + 32) * 1024 + k0 + lc];
    float4 c0 = *(const float4*)&Up[(size_t)(j0 + lr) * 1024 + k0 + lc];
    float4 c1 = *(const float4*)&Up[(size_t)(j0 + lr + 32) * 1024 + k0 + lc];
    __syncthreads();
    As[lr][lc + 0] = a0.x; As[lr][lc + 1] = a0.y; As[lr][lc + 2] = a0.z; As[lr][lc + 3] = a0.w;
    As[lr + 32][lc + 0] = a1.x; As[lr + 32][lc + 1] = a1.y; As[lr + 32][lc + 2] = a1.z; As[lr + 32][lc + 3] = a1.w;
    Bs[lr][lc + 0] = c0.x; Bs[lr][lc + 1] = c0.y; Bs[lr][lc + 2] = c0.z; Bs[lr][lc + 3] = c0.w;
    Bs[lr + 32][lc + 0] = c1.x; Bs[lr + 32][lc + 1] = c1.y; Bs[lr + 32][lc + 2] = c1.z; Bs[lr + 32][lc + 3] = c1.w;
    __syncthreads();
#pragma unroll
    for (int k = 0; k < 32; ++k) {
      float a0v = As[ty * 4 + 0][k], a1v = As[ty * 4 + 1][k];
      float a2v = As[ty * 4 + 2][k], a3v = As[ty * 4 + 3][k];
      float b0v = Bs[tx * 4 + 0][k], b1v = Bs[tx * 4 + 1][k];
      float b2v = Bs[tx * 4 + 2][k], b3v = Bs[tx * 4 + 3][k];
      acc[0][0] += a0v * b0v; acc[0][1] += a0v * b1v; acc[0][2] += a0v * b2v; acc[0][3] += a0v * b3v;
      acc[1][0] += a1v * b0v; acc[1][1] += a1v * b1v; acc[1][2] += a1v * b2v; acc[1][3] += a1v * b3v;
      acc[2][0] += a2v * b0v; acc[2][1] += a2v * b1v; acc[2][2] += a2v * b2v; acc[2][3] += a2v * b3v;
      acc[3][0] += a3v * b0v; acc[3][1] += a3v * b1v; acc[3][2] += a3v * b2v; acc[3][3] += a3v * b3v;
    }
  }
  // scatter epilogue: xpre4[(t*1024 + j)*4 + g]
#pragma unroll
  for (int i = 0; i < 4; ++i) {
    size_t rowi = (size_t)(m0 + ty * 4 + i);
#pragma unroll
    for (int j = 0; j < 4; ++j) {
      int jj = j0 + tx * 4 + j;
      float v = acc[i][j] + Bp[jj];
      xpre4[(rowi * 1024 + jj) * 4 + g] = __float2half(v);
    }
  }
}

// ---------------- persistent recurrence kernel --------------------------------
__global__ __launch_bounds__(512, 1) void rnnk(
    const uint32_t* __restrict__ wpack,  // [64][512][64] dwords, per-lane packed
    const __half* __restrict__ xpre4,    // [4096][1024][4] fp16
    uint32_t* tagged,                    // [2][1024] tagged h dwords
    float* __restrict__ out) {           // [4096][1024] f32
  __shared__ uint32_t wl[512 * 64];      // 128 KB weights, slot-swizzled
  __shared__ uint32_t hl[2][640];        // packed h pairs, stride-20 chunks
  const int wg = blockIdx.x;
  const int tid = threadIdx.x;
  const int wave = tid >> 6, lane = tid & 63;
  const int k = tid & 31;            // h-chunk: cols [32k, 32k+32)
  const int rloc = tid >> 5;         // 0..15
  const int row = (wg << 4) + rloc;  // 0..1023
  const bool w0 = (wave == 0);
  const bool leader = (k == 0);

  // ---- stage this lane's 64 weight dwords into LDS, slot-rotated by tid ----
  // logical quad j (gate g=j>>2, sub m=j&3) lives at physical slot (j+tid)&15,
  // so a fixed-j read across 64 lanes spreads evenly over all 8 bank-quads.
  {
    const u32x4* wp = reinterpret_cast<const u32x4*>(wpack) +
                      (((size_t)wg << 9) + (size_t)tid) * 16;
#pragma unroll
    for (int j = 0; j < 16; ++j) {
      u32x4 w4 = wp[j];
      *reinterpret_cast<u32x4*>(&wl[(tid << 6) + (((j + tid) & 15) << 2)]) = w4;
    }
  }
  __syncthreads();

  float s = 0.f;  // cell state (leader lanes only)

  for (int t = 0; t < T_STEPS; ++t) {
    const int buf = t & 1;

    // ---- ds_read the 16 weight quads FIRST: issued before the poll/barrier,
    // LDS service overlaps the wait; barrier pins results in VGPRs. ----
    u32x4 wq[16];
#pragma unroll
    for (int j = 0; j < 16; ++j)
      wq[j] = *reinterpret_cast<const u32x4*>(
          &wl[(tid << 6) + (((j + tid) & 15) << 2)]);

    // leader prefetch: all 4 gate pre-activations in ONE 8B load
    float xf = 0.f, xc = 0.f, xg = 0.f, xq = 0.f;
    if (leader) {
      uint2 xv = *reinterpret_cast<const uint2*>(
          reinterpret_cast<const uint32_t*>(xpre4) +
          ((((size_t)t << 10) + row) << 1));
      __half2 lo = __builtin_bit_cast(__half2, xv.x);
      __half2 hi = __builtin_bit_cast(__half2, xv.y);
      xf = __half2float(lo.x); xc = __half2float(lo.y);
      xg = __half2float(hi.x); xq = __half2float(hi.y);
    }

    // --- wave 0: poll h_{t-1} (16 tagged dwords/lane via 4x dwordx4 sc0 sc1) ---
    if (w0) {
      const uint32_t* tb = tagged + (buf << 10) + (lane << 4);
      const uint32_t tg = (uint32_t)t;
      u32x4 v0, v1, v2, v3;
      bool ok;
      do {
        asm volatile(
            "global_load_dwordx4 %0, %4, off sc0 sc1\n\t"
            "global_load_dwordx4 %1, %5, off sc0 sc1\n\t"
            "global_load_dwordx4 %2, %6, off sc0 sc1\n\t"
            "global_load_dwordx4 %3, %7, off sc0 sc1\n\t"
            "s_waitcnt vmcnt(0)"
            : "=&v"(v0), "=&v"(v1), "=&v"(v2), "=&v"(v3)
            : "v"(tb), "v"(tb + 4), "v"(tb + 8), "v"(tb + 12)
            : "memory");
        ok = (v0.x >> 16) == tg && (v0.y >> 16) == tg && (v0.z >> 16) == tg &&
             (v0.w >> 16) == tg && (v1.x >> 16) == tg && (v1.y >> 16) == tg &&
             (v1.z >> 16) == tg && (v1.w >> 16) == tg && (v2.x >> 16) == tg &&
             (v2.y >> 16) == tg && (v2.z >> 16) == tg && (v2.w >> 16) == tg &&
             (v3.x >> 16) == tg && (v3.y >> 16) == tg && (v3.z >> 16) == tg &&
             (v3.w >> 16) == tg;
      } while (!ok);
      // pack 16 tagged dwords -> 8 fp16-pair dwords; p = 8*lane + j
      uint32_t pk[8];
      pk[0] = (v0.x & 0xffffu) | (v0.y << 16);
      pk[1] = (v0.z & 0xffffu) | (v0.w << 16);
      pk[2] = (v1.x & 0xffffu) | (v1.y << 16);
      pk[3] = (v1.z & 0xffffu) | (v1.w << 16);
      pk[4] = (v2.x & 0xffffu) | (v2.y << 16);
      pk[5] = (v2.z & 0xffffu) | (v2.w << 16);
      pk[6] = (v3.x & 0xffffu) | (v3.y << 16);
      pk[7] = (v3.z & 0xffffu) | (v3.w << 16);
      // dst: chunk c = p>>4 = lane>>1, idx = p&15 = 8*(lane&1)+j, stride 20
      uint32_t* dst = &hl[buf][20 * (lane >> 1) + ((lane & 1) << 3)];
      u32x4 wA, wB;
      wA.x = pk[0]; wA.y = pk[1]; wA.z = pk[2]; wA.w = pk[3];
      wB.x = pk[4]; wB.y = pk[5]; wB.z = pk[6]; wB.w = pk[7];
      *reinterpret_cast<u32x4*>(dst) = wA;
      *reinterpret_cast<u32x4*>(dst + 4) = wB;
    }
    __syncthreads();  // hl[buf] ready — the only barrier per step

    // --- own h chunk: 4 quads at stride-20 (bank-spread) ---
    u32x4 hq[4];
#pragma unroll
    for (int m = 0; m < 4; ++m)
      hq[m] = *reinterpret_cast<const u32x4*>(&hl[buf][20 * k + (m << 2)]);

    // --- 4 gates x 32 MACs from registers ---
    float a0 = 0.f, a1 = 0.f, a2 = 0.f, a3 = 0.f;
#pragma unroll
    for (int m = 0; m < 4; ++m) {
      u32x4 w4 = wq[m];
      a0 = dot2(w4.x, hq[m].x, a0); a0 = dot2(w4.y, hq[m].y, a0);
      a0 = dot2(w4.z, hq[m].z, a0); a0 = dot2(w4.w, hq[m].w, a0);
    }
#pragma unroll
    for (int m = 0; m < 4; ++m) {
      u32x4 w4 = wq[4 + m];
      a1 = dot2(w4.x, hq[m].x, a1); a1 = dot2(w4.y, hq[m].y, a1);
      a1 = dot2(w4.z, hq[m].z, a1); a1 = dot2(w4.w, hq[m].w, a1);
    }
#pragma unroll
    for (int m = 0; m < 4; ++m) {
      u32x4 w4 = wq[8 + m];
      a2 = dot2(w4.x, hq[m].x, a2); a2 = dot2(w4.y, hq[m].y, a2);
      a2 = dot2(w4.z, hq[m].z, a2); a2 = dot2(w4.w, hq[m].w, a2);
    }
#pragma unroll
    for (int m = 0; m < 4; ++m) {
      u32x4 w4 = wq[12 + m];
      a3 = dot2(w4.x, hq[m].x, a3); a3 = dot2(w4.y, hq[m].y, a3);
      a3 = dot2(w4.z, hq[m].z, a3); a3 = dot2(w4.w, hq[m].w, a3);
    }

    // --- reduce across the 32 chunk-lanes of this row (stays in 32-lane half) ---
#pragma unroll
    for (int mk = 1; mk <= 16; mk <<= 1) {
      a0 += __shfl_xor(a0, mk);
      a1 += __shfl_xor(a1, mk);
      a2 += __shfl_xor(a2, mk);
      a3 += __shfl_xor(a3, mk);
    }

    // --- leader epilogue: gates, s-update, h, publish ---
    if (leader) {
      float f = sigf(a0 + xf);
      float cc = sigf(a1 + xc);
      float gg = sigf(a2 + xg);
      float q = sigf(a3 + xq);
      s = f * s + gg * cc;
      float e2 = __expf(2.f * s);  // s >= 0 always; inf -> th = 1
      float th = 1.f - 2.f / (e2 + 1.f);
      float h = th * q;
      out[(size_t)t * HDIM + row] = h;
      uint32_t dw = ((uint32_t)(t + 1) << 16) |
                    (uint32_t)__half_as_ushort(__float2half(h));
      __hip_atomic_store(&tagged[(((t + 1) & 1) << 10) + row], dw,
                         __ATOMIC_RELAXED, __HIP_MEMORY_SCOPE_AGENT);
    }
    // no trailing barrier: wave0's next hl write targets hl[buf^1] (last read
    // at step t-1, done before this step's barrier), and its poll for t+1
    // succeeds only after every row published t+1.
  }
}

extern "C" void kernel_launch(void* const* d_in, const int* in_sizes, int n_in,
                              void* d_out, int out_size, void* d_ws, size_t ws_size,
                              hipStream_t stream) {
  const float* x  = (const float*)d_in[0];
  const float* Uf = (const float*)d_in[1];
  const float* Wf = (const float*)d_in[2];
  const float* Bf = (const float*)d_in[3];
  const float* Ug = (const float*)d_in[4];
  const float* Wg = (const float*)d_in[5];
  const float* Bg = (const float*)d_in[6];
  const float* Uq = (const float*)d_in[7];
  const float* Wq = (const float*)d_in[8];
  const float* Bq = (const float*)d_in[9];
  const float* U  = (const float*)d_in[10];
  const float* W  = (const float*)d_in[11];
  const float* B  = (const float*)d_in[12];
  float* out = (float*)d_out;

  // ws layout: [0,32MB) xpre4 fp16 [4096][1024][4]; [32MB,40MB) wpack 2M dwords;
  // [40MB,+8KB) tagged h dwords [2][1024].
  char* ws = (char*)d_ws;
  __half* xpre4 = (__half*)ws;
  uint32_t* wpack = (uint32_t*)(ws + (size_t)32 * 1024 * 1024);
  uint32_t* tagged = (uint32_t*)(ws + (size_t)40 * 1024 * 1024);

  // gate order everywhere: 0=f(Uf,Wf,Bf) 1=c(U,W,B) 2=g(Ug,Wg,Bg) 3=q(Uq,Wq,Bq)
  convw<<<8192, 256, 0, stream>>>(Wf, W, Wg, Wq, wpack);
  zerok<<<8, 256, 0, stream>>>(tagged);
  gemmk<<<dim3(64, 64), 256, 0, stream>>>(x, Uf, U, Ug, Uq, Bf, B, Bg, Bq, xpre4);
  rnnk<<<NWG, 512, 0, stream>>>(wpack, xpre4, tagged, out);
}